// Round 1
// 611.144 us; speedup vs baseline: 1.2684x; 1.2684x over previous
//
#include <hip/hip_runtime.h>
#include <stdint.h>

// Problem constants (exact multiples of tile sizes — no bounds checks)
#define M_DIM 4096      // 2*2048 rows of x
#define K_DIM 4096      // in_features
#define N_DIM 11008     // out_features
#define KW_DIM 2048     // weight_q words per row (each int32 holds 1 byte = 2 nibbles)

typedef __bf16 bf16x8 __attribute__((ext_vector_type(8)));
typedef float  f32x4  __attribute__((ext_vector_type(4)));

typedef __attribute__((address_space(1))) const void gv_t;  // global
typedef __attribute__((address_space(3))) void lv_t;        // LDS

__device__ inline unsigned int bf16_rne_bits(float f) {
    unsigned int u = __float_as_uint(f);
    return (u + 0x7FFFu + ((u >> 16) & 1u)) >> 16;
}
__device__ inline unsigned int pack_bf16_pair(float lo, float hi) {
    return bf16_rne_bits(lo) | (bf16_rne_bits(hi) << 16);
}

#define NF4_INIT  {-1.0f, -0.6961928f, -0.525073f, -0.39491748f, \
                   -0.28444138f, -0.18477343f, -0.09105602f, 0.0f, \
                   0.07958029f, 0.1609302f, 0.2461123f, 0.33791524f, \
                   0.44070983f, 0.56261897f, 0.72295684f, 1.0f}

// ---------------- Pass 1a: dequantize Wq (int32 words, 1 byte each) -> bf16 ----------------
__global__ __launch_bounds__(256)
void dequant_w(const int4* __restrict__ Wq4, uint4* __restrict__ Wb4)
{
    __shared__ unsigned int lutr[256 * 32];
    const int t = threadIdx.x;
    {
        const float LUT[16] = NF4_INIT;
        const int c0 = t & 31;
        #pragma unroll
        for (int j = 0; j < 32; ++j) {
            const int e = (t >> 5) * 32 + j;
            lutr[e * 32 + c0] = pack_bf16_pair(LUT[(e >> 4) & 15], LUT[e & 15]);
        }
    }
    __syncthreads();
    const int c = t & 31;
    size_t gid = (size_t)blockIdx.x * 256 + t;
    const size_t stride = 2752u * 256u;
    #pragma unroll
    for (int it = 0; it < 8; ++it) {
        int4 w = Wq4[gid];
        uint4 o;
        o.x = lutr[(w.x & 255) * 32 + c];
        o.y = lutr[(w.y & 255) * 32 + c];
        o.z = lutr[(w.z & 255) * 32 + c];
        o.w = lutr[(w.w & 255) * 32 + c];
        Wb4[gid] = o;
        gid += stride;
    }
}

// ---------------- Pass 1b: X fp32 -> bf16 ----------------
__global__ __launch_bounds__(256)
void convert_x(const float4* __restrict__ X4, uint4* __restrict__ Xb4)
{
    size_t gid = (size_t)blockIdx.x * 256 + threadIdx.x;
    float4 a = X4[gid * 2];
    float4 b = X4[gid * 2 + 1];
    uint4 o;
    o.x = pack_bf16_pair(a.x, a.y);
    o.y = pack_bf16_pair(a.z, a.w);
    o.z = pack_bf16_pair(b.x, b.y);
    o.w = pack_bf16_pair(b.z, b.w);
    Xb4[gid] = o;
}

// ---------------- Pass 2: bf16 GEMM — 256x256 tile, 8-wave, 4-deep LDS ring ----------------
// Structure: T1 (XCD swizzle) + T2 (XOR bank swizzle) + T3/T4 (phased schedule, counted
// vmcnt(8), never drained to 0 in the loop) + T5 (setprio around MFMA clusters).
// BK=32, 4 LDS buffers (A 4x16KB + B 4x16KB = 128 KiB), staging 3 K-tiles ahead.
// Per K-tile: 2 phases x {ds_read frags; issue 2 global_load_lds; barrier; lgkmcnt(0);
// setprio(1); 16 MFMA; setprio(0); barrier}; vmcnt(8) once per K-tile before end barrier.
//
// Swizzle: LDS tile rows are 64 B (32 bf16). byte ^= ((byte>>7)&3)<<4 — involution,
// preserves row (bits>=6 untouched except via row pair bits feeding the XOR source),
// keeps 16-B blocks intact. Staging writes LINEAR LDS (gload_lds requirement) from an
// inverse-swizzled GLOBAL source; ds_read applies the same XOR. 8-lane issue groups then
// cover 8 distinct 16-B bank quads (conflict-free); 16-lane groups are 2-way (free, m136).
constexpr int GBM = 256, GBN = 256, GBK = 32;
constexpr int NKT = K_DIM / GBK;             // 128
constexpr int NT2 = N_DIM / GBN;             // 43
constexpr int GRID2 = (M_DIM / GBM) * NT2;   // 688 = 8 * 86 (bijective XCD swizzle)

__global__ __launch_bounds__(512, 2)
void gemm_8ph(const unsigned short* __restrict__ Xb, const unsigned short* __restrict__ Wb,
              const float* __restrict__ scale, const float* __restrict__ bias,
              float* __restrict__ Out)
{
    __shared__ __align__(16) char lds[131072];
    char* const ldsA = lds;            // 4 buffers x 16 KB (256 rows x 64 B)
    char* const ldsB = lds + 65536;    // 4 buffers x 16 KB

    const int t = threadIdx.x;
    const int lane = t & 63;
    const int wv = t >> 6;             // 0..7
    const int wr = wv >> 2;            // 0..1 : wave owns A rows [wr*128, wr*128+128)
    const int wc = wv & 3;             // 0..3 : wave owns B rows [wc*64, wc*64+64)
    const int l16 = lane & 15, quad = lane >> 4;

    // XCD-aware bijective block swizzle (688 % 8 == 0)
    const int bid = blockIdx.x;
    const int wg = (bid & 7) * (GRID2 / 8) + (bid >> 3);
    const int m0 = (wg / NT2) * GBM;
    const int n0 = (wg % NT2) * GBN;

    // LDS fragment-read byte offsets (within a 16 KB buffer), swizzled.
    // row = base + l16; (row>>1)&3 == (l16>>1)&3 since bases are multiples of 16.
    const int sw  = ((quad ^ ((l16 >> 1) & 3)) << 4);
    const int a_rd = (wr * 128 + l16) * 64 + sw;   // + mh*4096 + i*1024
    const int b_rd = (wc * 64  + l16) * 64 + sw;   // + j*1024

    // Staging: thread t covers LDS-linear bytes [t*16, t*16+16) of an 8 KB half-tile
    // (row = t>>2, slot = t&3). Global source uses the inverse (== same) swizzle:
    const int srow  = t >> 2;                       // 0..127
    const int sslot = (t & 3) ^ ((t >> 3) & 3);     // swizzled 16-B slot
    const unsigned short* sA = Xb + (size_t)(m0 + srow) * K_DIM + sslot * 8;
    const unsigned short* sB = Wb + (size_t)(n0 + srow) * K_DIM + sslot * 8;
    const int sdst = t * 16;

    f32x4 acc[8][4];
    #pragma unroll
    for (int i = 0; i < 8; ++i)
        #pragma unroll
        for (int j = 0; j < 4; ++j)
            acc[i][j] = f32x4{0.f, 0.f, 0.f, 0.f};

    // ---- prologue: stage K-tiles 0,1,2 into buffers 0,1,2 (12 loads/thread) ----
    #pragma unroll
    for (int k0 = 0; k0 < 3; ++k0) {
        char* Ad = ldsA + k0 * 16384;
        char* Bd = ldsB + k0 * 16384;
        __builtin_amdgcn_global_load_lds((gv_t*)(sA + k0 * 32),
                                         (lv_t*)(Ad + sdst), 16, 0, 0);
        __builtin_amdgcn_global_load_lds((gv_t*)(sA + k0 * 32 + (size_t)128 * K_DIM),
                                         (lv_t*)(Ad + 8192 + sdst), 16, 0, 0);
        __builtin_amdgcn_global_load_lds((gv_t*)(sB + k0 * 32),
                                         (lv_t*)(Bd + sdst), 16, 0, 0);
        __builtin_amdgcn_global_load_lds((gv_t*)(sB + k0 * 32 + (size_t)128 * K_DIM),
                                         (lv_t*)(Bd + 8192 + sdst), 16, 0, 0);
    }
    asm volatile("s_waitcnt vmcnt(8)" ::: "memory");   // K-tile 0 fully landed
    __builtin_amdgcn_s_barrier();

    #pragma unroll 4
    for (int kt = 0; kt < NKT; ++kt) {
        const char* Ab = ldsA + (kt & 3) * 16384;
        const char* Bb = ldsB + (kt & 3) * 16384;
        // stage K-tile kt+3 into buffer (kt+3)&3 (last read at kt-1 — safe).
        // Tail: clamp to NKT-1 (dummy re-stage keeps vmcnt counting uniform; the
        // target buffers are already fully consumed, never read again).
        const int ktS = (kt + 3 < NKT) ? (kt + 3) : (NKT - 1);
        char* AdS = ldsA + ((kt + 3) & 3) * 16384;
        char* BdS = ldsB + ((kt + 3) & 3) * 16384;

        bf16x8 af[4], bfr[4];

        // ---------------- Phase 1: quadrant mh=0 (8 ds_read + 2 stage) ----------------
        #pragma unroll
        for (int i = 0; i < 4; ++i)
            af[i] = *reinterpret_cast<const bf16x8*>(Ab + a_rd + i * 1024);
        #pragma unroll
        for (int j = 0; j < 4; ++j)
            bfr[j] = *reinterpret_cast<const bf16x8*>(Bb + b_rd + j * 1024);
        __builtin_amdgcn_global_load_lds((gv_t*)(sA + ktS * 32),
                                         (lv_t*)(AdS + sdst), 16, 0, 0);
        __builtin_amdgcn_global_load_lds((gv_t*)(sA + ktS * 32 + (size_t)128 * K_DIM),
                                         (lv_t*)(AdS + 8192 + sdst), 16, 0, 0);
        __builtin_amdgcn_s_barrier();
        asm volatile("s_waitcnt lgkmcnt(0)" ::: "memory");
        __builtin_amdgcn_s_setprio(1);
        #pragma unroll
        for (int i = 0; i < 4; ++i)
            #pragma unroll
            for (int j = 0; j < 4; ++j)
                acc[i][j] = __builtin_amdgcn_mfma_f32_16x16x32_bf16(af[i], bfr[j], acc[i][j], 0, 0, 0);
        __builtin_amdgcn_s_setprio(0);
        __builtin_amdgcn_s_barrier();

        // ---------------- Phase 2: quadrant mh=1 (4 ds_read + 2 stage + vmcnt) --------
        #pragma unroll
        for (int i = 0; i < 4; ++i)
            af[i] = *reinterpret_cast<const bf16x8*>(Ab + a_rd + 4096 + i * 1024);
        __builtin_amdgcn_global_load_lds((gv_t*)(sB + ktS * 32),
                                         (lv_t*)(BdS + sdst), 16, 0, 0);
        __builtin_amdgcn_global_load_lds((gv_t*)(sB + ktS * 32 + (size_t)128 * K_DIM),
                                         (lv_t*)(BdS + 8192 + sdst), 16, 0, 0);
        __builtin_amdgcn_s_barrier();
        asm volatile("s_waitcnt lgkmcnt(0)" ::: "memory");
        __builtin_amdgcn_s_setprio(1);
        #pragma unroll
        for (int i = 0; i < 4; ++i)
            #pragma unroll
            for (int j = 0; j < 4; ++j)
                acc[4 + i][j] = __builtin_amdgcn_mfma_f32_16x16x32_bf16(af[i], bfr[j], acc[4 + i][j], 0, 0, 0);
        __builtin_amdgcn_s_setprio(0);
        // counted wait: newest 8 outstanding = K-tiles kt+2,kt+3 -> kt+1 landed.
        asm volatile("s_waitcnt vmcnt(8)" ::: "memory");
        __builtin_amdgcn_s_barrier();
    }

    // drain dummy DMA before this block's LDS can be handed to a successor block
    asm volatile("s_waitcnt vmcnt(0)" ::: "memory");

    // ---- epilogue: out[m][n] = acc * scale[n] + bias[n] ----
    // C/D frag: col = lane&15 (n), row = quad*4 + reg (m)
    #pragma unroll
    for (int j = 0; j < 4; ++j) {
        const int n = n0 + wc * 64 + j * 16 + l16;
        const float s  = scale[n];
        const float bz = bias[n];
        #pragma unroll
        for (int ii = 0; ii < 8; ++ii) {
            const int m = m0 + wr * 128 + ii * 16 + quad * 4;
            float* op = Out + (size_t)m * N_DIM + n;
            #pragma unroll
            for (int r = 0; r < 4; ++r)
                op[(size_t)r * N_DIM] = acc[ii][j][r] * s + bz;
        }
    }
}

// ---------------- Fallback: fused single-pass kernel (ws too small) ----------------
constexpr int BM = 128, BN = 128, BK = 64;
constexpr int F_LDK = BK + 8;
__global__ __launch_bounds__(256, 2)
void nf4_gemm_fused(const float* __restrict__ X, const int* __restrict__ Wq,
                    const float* __restrict__ scale, const float* __restrict__ bias,
                    float* __restrict__ Out)
{
    __shared__ __align__(16) unsigned short As[BM * F_LDK];
    __shared__ __align__(16) unsigned short Bs[BN * F_LDK];
    __shared__ unsigned int lut2[256];

    const int t = threadIdx.x;
    const int ntiles = N_DIM / BN;
    const int mtile = blockIdx.x / ntiles;
    const int ntile = blockIdx.x % ntiles;
    const int m0 = mtile * BM, n0 = ntile * BN;

    {
        const float LUT[16] = NF4_INIT;
        lut2[t] = pack_bf16_pair(LUT[(t >> 4) & 15], LUT[t & 15]);
    }

    const int lane = t & 63;
    const int wv = t >> 6;
    const int wr = wv >> 1, wc = wv & 1;
    const int l16 = lane & 15, quad = lane >> 4;

    const int a_r = t >> 4, a_c = (t & 15) * 4;
    const int b_r = t >> 3, b_c = (t & 7) * 4;

    const float* aptr = X + (m0 + a_r) * K_DIM + a_c;
    const int*   bptr = Wq + (n0 + b_r) * KW_DIM + b_c;

    f32x4 acc[4][4];
    #pragma unroll
    for (int i = 0; i < 4; ++i)
        #pragma unroll
        for (int j = 0; j < 4; ++j)
            acc[i][j] = f32x4{0.f, 0.f, 0.f, 0.f};

    for (int kt = 0; kt < K_DIM / BK; ++kt) {
        float4 av[8];
        int4   bv[4];
        #pragma unroll
        for (int i = 0; i < 8; ++i)
            av[i] = *reinterpret_cast<const float4*>(aptr + i * 16 * K_DIM);
        #pragma unroll
        for (int i = 0; i < 4; ++i)
            bv[i] = *reinterpret_cast<const int4*>(bptr + i * 32 * KW_DIM);
        aptr += BK;
        bptr += BK / 2;

        __syncthreads();

        #pragma unroll
        for (int i = 0; i < 8; ++i) {
            uint2 p;
            p.x = pack_bf16_pair(av[i].x, av[i].y);
            p.y = pack_bf16_pair(av[i].z, av[i].w);
            *reinterpret_cast<uint2*>(&As[(a_r + i * 16) * F_LDK + a_c]) = p;
        }
        #pragma unroll
        for (int i = 0; i < 4; ++i) {
            uint4 q;
            q.x = lut2[bv[i].x & 255];
            q.y = lut2[bv[i].y & 255];
            q.z = lut2[bv[i].z & 255];
            q.w = lut2[bv[i].w & 255];
            *reinterpret_cast<uint4*>(&Bs[(b_r + i * 32) * F_LDK + b_c * 2]) = q;
        }
        __syncthreads();

        #pragma unroll
        for (int ks = 0; ks < 2; ++ks) {
            bf16x8 af[4], bfr[4];
            const int kb = ks * 32 + quad * 8;
            #pragma unroll
            for (int i = 0; i < 4; ++i)
                af[i] = *reinterpret_cast<const bf16x8*>(&As[(wr * 64 + i * 16 + l16) * F_LDK + kb]);
            #pragma unroll
            for (int j = 0; j < 4; ++j)
                bfr[j] = *reinterpret_cast<const bf16x8*>(&Bs[(wc * 64 + j * 16 + l16) * F_LDK + kb]);
            #pragma unroll
            for (int i = 0; i < 4; ++i)
                #pragma unroll
                for (int j = 0; j < 4; ++j)
                    acc[i][j] = __builtin_amdgcn_mfma_f32_16x16x32_bf16(af[i], bfr[j], acc[i][j], 0, 0, 0);
        }
    }

    #pragma unroll
    for (int j = 0; j < 4; ++j) {
        const int n = n0 + wc * 64 + j * 16 + l16;
        const float s  = scale[n];
        const float bz = bias[n];
        #pragma unroll
        for (int i = 0; i < 4; ++i) {
            const int m = m0 + wr * 64 + i * 16 + quad * 4;
            float* op = Out + (size_t)m * N_DIM + n;
            #pragma unroll
            for (int r = 0; r < 4; ++r)
                op[(size_t)r * N_DIM] = acc[i][j][r] * s + bz;
        }
    }
}

extern "C" void kernel_launch(void* const* d_in, const int* in_sizes, int n_in,
                              void* d_out, int out_size, void* d_ws, size_t ws_size,
                              hipStream_t stream) {
    const float* X     = (const float*)d_in[0];
    const int*   Wq    = (const int*)d_in[1];
    const float* scale = (const float*)d_in[2];
    const float* bias  = (const float*)d_in[3];
    float* Out = (float*)d_out;

    const size_t WB_BYTES = (size_t)N_DIM * K_DIM * 2;   // 90,177,536
    const size_t XB_BYTES = (size_t)M_DIM * K_DIM * 2;   // 33,554,432

    if (ws_size >= WB_BYTES + XB_BYTES) {
        unsigned short* Wb = (unsigned short*)d_ws;
        unsigned short* Xb = (unsigned short*)((char*)d_ws + WB_BYTES);
        dequant_w<<<2752, 256, 0, stream>>>((const int4*)Wq, (uint4*)Wb);
        convert_x<<<8192, 256, 0, stream>>>((const float4*)X, (uint4*)Xb);
        gemm_8ph<<<GRID2, 512, 0, stream>>>(Xb, Wb, scale, bias, Out);
    } else {
        nf4_gemm_fused<<<(M_DIM / BM) * (N_DIM / BN), 256, 0, stream>>>(X, Wq, scale, bias, Out);
    }
}